// Round 8
// baseline (31.723 us; speedup 1.0000x reference)
//
#include <hip/hip_runtime.h>

// PIT loss: x,y [B=8, C=4, CH=2, T=262144] f32. D = CH*T = 524288.
// dists[b,i,j] = (sum(y[b,i]^2) + sum(x[b,j]^2) - 2*sum(x[b,j]*y[b,i])) / D
// total = sum_b min_p sum_i dists[b,i,perm[p][i]]; assignments[b] = argmin perm.
//
// R8: R7 (nt loads, transposed ws, coalesced finalize) + BPB 64->128:
// occupancy/concurrency re-probe in the post-nt pure-HBM-stream regime
// (the pre-nt probe R2 was flat because the L3-hit path was the limiter).

#define BATCH   8
#define CDIM    4
#define DLEN    (2 * 262144)        // 524288 scalars per (b, c)
#define F4_PER_C (DLEN / 4)         // 131072 float4 per channel
#define BPB     128                 // blocks per batch
#define TPB     256
#define NVAL    24                  // 4 sx + 4 sy + 16 cross
#define NBLOCKS (BATCH * BPB)       // 1024

typedef float f4 __attribute__((ext_vector_type(4)));

// itertools.permutations(range(4)) lexicographic order
__device__ __constant__ int PERMS[24][4] = {
    {0,1,2,3},{0,1,3,2},{0,2,1,3},{0,2,3,1},{0,3,1,2},{0,3,2,1},
    {1,0,2,3},{1,0,3,2},{1,2,0,3},{1,2,3,0},{1,3,0,2},{1,3,2,0},
    {2,0,1,3},{2,0,3,1},{2,1,0,3},{2,1,3,0},{2,3,0,1},{2,3,1,0},
    {3,0,1,2},{3,0,2,1},{3,1,0,2},{3,1,2,0},{3,2,0,1},{3,2,1,0}
};

__global__ __launch_bounds__(TPB) void pit_reduce(const float* __restrict__ x,
                                                  const float* __restrict__ y,
                                                  float* __restrict__ ws) {
    const int b   = blockIdx.x / BPB;
    const int blk = blockIdx.x % BPB;
    const int tid = threadIdx.x;

    const int f4_per_block = F4_PER_C / BPB;     // 1024
    const int iters        = f4_per_block / TPB; // 4
    const int base_f4      = blk * f4_per_block;

    const f4* __restrict__ xb = (const f4*)(x + (size_t)b * CDIM * DLEN);
    const f4* __restrict__ yb = (const f4*)(y + (size_t)b * CDIM * DLEN);

    float sx[4] = {0.f, 0.f, 0.f, 0.f};
    float sy[4] = {0.f, 0.f, 0.f, 0.f};
    float cr[4][4] = {};

    for (int it = 0; it < iters; ++it) {
        const int p = base_f4 + it * TPB + tid;
        f4 xv[4], yv[4];
#pragma unroll
        for (int c = 0; c < 4; ++c)
            xv[c] = __builtin_nontemporal_load(&xb[(size_t)c * F4_PER_C + p]);
#pragma unroll
        for (int c = 0; c < 4; ++c)
            yv[c] = __builtin_nontemporal_load(&yb[(size_t)c * F4_PER_C + p]);
#pragma unroll
        for (int c = 0; c < 4; ++c) {
            sx[c] += xv[c].x * xv[c].x + xv[c].y * xv[c].y +
                     xv[c].z * xv[c].z + xv[c].w * xv[c].w;
            sy[c] += yv[c].x * yv[c].x + yv[c].y * yv[c].y +
                     yv[c].z * yv[c].z + yv[c].w * yv[c].w;
        }
#pragma unroll
        for (int i = 0; i < 4; ++i)
#pragma unroll
            for (int j = 0; j < 4; ++j)
                cr[i][j] += yv[i].x * xv[j].x + yv[i].y * xv[j].y +
                            yv[i].z * xv[j].z + yv[i].w * xv[j].w;
    }

    // pack 24 accumulators: [0..3]=sx, [4..7]=sy, [8..23]=cr[i][j]
    float v[NVAL];
#pragma unroll
    for (int c = 0; c < 4; ++c) { v[c] = sx[c]; v[4 + c] = sy[c]; }
#pragma unroll
    for (int i = 0; i < 4; ++i)
#pragma unroll
        for (int j = 0; j < 4; ++j) v[8 + i * 4 + j] = cr[i][j];

    // wave64 tree reduce (deterministic)
#pragma unroll
    for (int k = 0; k < NVAL; ++k) {
#pragma unroll
        for (int off = 32; off > 0; off >>= 1)
            v[k] += __shfl_down(v[k], off);
    }

    __shared__ float red[4][NVAL];
    const int wave = tid >> 6, lane = tid & 63;
    if (lane == 0) {
#pragma unroll
        for (int k = 0; k < NVAL; ++k) red[wave][k] = v[k];
    }
    __syncthreads();
    if (tid < NVAL) {
        float s = red[0][tid] + red[1][tid] + red[2][tid] + red[3][tid];
        // transposed: ws[k][global_block] -> contiguous per-k rows of 1024 floats
        ws[(size_t)tid * NBLOCKS + (b * BPB + blk)] = s;
    }
}

__global__ __launch_bounds__(256) void pit_finalize(const float* __restrict__ ws,
                                                    float* __restrict__ out) {
    __shared__ double stage[BATCH][NVAL];   // summed partials
    __shared__ double dists[BATCH][4][4];
    __shared__ double mins[BATCH];
    const int tid = threadIdx.x;

    // 192 active threads, (k major, b minor): the whole block reads the
    // 96 KiB ws span fully coalesced as float4.
    if (tid < BATCH * NVAL) {
        const int k = tid / BATCH, bb = tid % BATCH;
        const f4* p = (const f4*)(ws + (size_t)k * NBLOCKS + bb * BPB);
        double s0 = 0.0, s1 = 0.0, s2 = 0.0, s3 = 0.0;
#pragma unroll
        for (int q = 0; q < 32; q += 4) {        // 32 f4 = 128 partials
            f4 a = p[q + 0], c = p[q + 1], d = p[q + 2], e = p[q + 3];
            s0 += (double)a.x + (double)a.y + (double)a.z + (double)a.w;
            s1 += (double)c.x + (double)c.y + (double)c.z + (double)c.w;
            s2 += (double)d.x + (double)d.y + (double)d.z + (double)d.w;
            s3 += (double)e.x + (double)e.y + (double)e.z + (double)e.w;
        }
        stage[bb][k] = (s0 + s1) + (s2 + s3);
    }
    __syncthreads();

    if (tid < BATCH * 16) {                 // 128 threads
        const int bb = tid / 16, ij = tid % 16, i = ij / 4, j = ij % 4;
        dists[bb][i][j] = (stage[bb][4 + i] + stage[bb][j]
                           - 2.0 * stage[bb][8 + i * 4 + j]) / (double)DLEN;
    }
    __syncthreads();

    if (tid < BATCH) {
        const int bb = tid;
        double best = 1e300;
        int bestp = 0;
        for (int p = 0; p < 24; ++p) {
            double c = 0.0;
#pragma unroll
            for (int i = 0; i < 4; ++i) c += dists[bb][i][PERMS[p][i]];
            if (c < best) { best = c; bestp = p; }   // strict < => first min (jnp.argmin)
        }
        mins[bb] = best;
#pragma unroll
        for (int i = 0; i < 4; ++i)
            out[1 + bb * 4 + i] = (float)PERMS[bestp][i];
    }
    __syncthreads();

    if (tid == 0) {
        double tot = 0.0;
        for (int bb = 0; bb < BATCH; ++bb) tot += mins[bb];
        out[0] = (float)tot;
    }
}

extern "C" void kernel_launch(void* const* d_in, const int* in_sizes, int n_in,
                              void* d_out, int out_size, void* d_ws, size_t ws_size,
                              hipStream_t stream) {
    const float* x = (const float*)d_in[0];
    const float* y = (const float*)d_in[1];
    float* out = (float*)d_out;
    float* ws  = (float*)d_ws;     // needs NVAL*NBLOCKS*4 = 98304 bytes

    pit_reduce<<<NBLOCKS, TPB, 0, stream>>>(x, y, ws);
    pit_finalize<<<1, 256, 0, stream>>>(ws, out);
}

// Round 9
// 28.324 us; speedup vs baseline: 1.1200x; 1.1200x over previous
//
#include <hip/hip_runtime.h>

// PIT loss: x,y [B=8, C=4, CH=2, T=262144] f32. D = CH*T = 524288.
// dists[b,i,j] = (sum(y[b,i]^2) + sum(x[b,j]^2) - 2*sum(x[b,j]*y[b,i])) / D
// total = sum_b min_p sum_i dists[b,i,perm[p][i]]; assignments[b] = argmin perm.
//
// R9: stream-locality probe. TPB 256->512, BPB 64->32 (256 blocks): same
// wave density as R7 (2 waves/SIMD) and same 8 iters/thread, but half the
// machine-wide stream count (2048 vs 4096) and 64 KiB contiguous ownership
// per stream. nt loads, transposed ws, coalesced finalize kept from R7.

#define BATCH   8
#define CDIM    4
#define DLEN    (2 * 262144)        // 524288 scalars per (b, c)
#define F4_PER_C (DLEN / 4)         // 131072 float4 per channel
#define BPB     32                  // blocks per batch
#define TPB     512
#define NVAL    24                  // 4 sx + 4 sy + 16 cross
#define NBLOCKS (BATCH * BPB)       // 256
#define NWAVES  (TPB / 64)          // 8

typedef float f4 __attribute__((ext_vector_type(4)));

// itertools.permutations(range(4)) lexicographic order
__device__ __constant__ int PERMS[24][4] = {
    {0,1,2,3},{0,1,3,2},{0,2,1,3},{0,2,3,1},{0,3,1,2},{0,3,2,1},
    {1,0,2,3},{1,0,3,2},{1,2,0,3},{1,2,3,0},{1,3,0,2},{1,3,2,0},
    {2,0,1,3},{2,0,3,1},{2,1,0,3},{2,1,3,0},{2,3,0,1},{2,3,1,0},
    {3,0,1,2},{3,0,2,1},{3,1,0,2},{3,1,2,0},{3,2,0,1},{3,2,1,0}
};

__global__ __launch_bounds__(TPB) void pit_reduce(const float* __restrict__ x,
                                                  const float* __restrict__ y,
                                                  float* __restrict__ ws) {
    const int b   = blockIdx.x / BPB;
    const int blk = blockIdx.x % BPB;
    const int tid = threadIdx.x;

    const int f4_per_block = F4_PER_C / BPB;     // 4096
    const int iters        = f4_per_block / TPB; // 8
    const int base_f4      = blk * f4_per_block;

    const f4* __restrict__ xb = (const f4*)(x + (size_t)b * CDIM * DLEN);
    const f4* __restrict__ yb = (const f4*)(y + (size_t)b * CDIM * DLEN);

    float sx[4] = {0.f, 0.f, 0.f, 0.f};
    float sy[4] = {0.f, 0.f, 0.f, 0.f};
    float cr[4][4] = {};

    for (int it = 0; it < iters; ++it) {
        const int p = base_f4 + it * TPB + tid;
        f4 xv[4], yv[4];
#pragma unroll
        for (int c = 0; c < 4; ++c)
            xv[c] = __builtin_nontemporal_load(&xb[(size_t)c * F4_PER_C + p]);
#pragma unroll
        for (int c = 0; c < 4; ++c)
            yv[c] = __builtin_nontemporal_load(&yb[(size_t)c * F4_PER_C + p]);
#pragma unroll
        for (int c = 0; c < 4; ++c) {
            sx[c] += xv[c].x * xv[c].x + xv[c].y * xv[c].y +
                     xv[c].z * xv[c].z + xv[c].w * xv[c].w;
            sy[c] += yv[c].x * yv[c].x + yv[c].y * yv[c].y +
                     yv[c].z * yv[c].z + yv[c].w * yv[c].w;
        }
#pragma unroll
        for (int i = 0; i < 4; ++i)
#pragma unroll
            for (int j = 0; j < 4; ++j)
                cr[i][j] += yv[i].x * xv[j].x + yv[i].y * xv[j].y +
                            yv[i].z * xv[j].z + yv[i].w * xv[j].w;
    }

    // pack 24 accumulators: [0..3]=sx, [4..7]=sy, [8..23]=cr[i][j]
    float v[NVAL];
#pragma unroll
    for (int c = 0; c < 4; ++c) { v[c] = sx[c]; v[4 + c] = sy[c]; }
#pragma unroll
    for (int i = 0; i < 4; ++i)
#pragma unroll
        for (int j = 0; j < 4; ++j) v[8 + i * 4 + j] = cr[i][j];

    // wave64 tree reduce (deterministic)
#pragma unroll
    for (int k = 0; k < NVAL; ++k) {
#pragma unroll
        for (int off = 32; off > 0; off >>= 1)
            v[k] += __shfl_down(v[k], off);
    }

    __shared__ float red[NWAVES][NVAL];
    const int wave = tid >> 6, lane = tid & 63;
    if (lane == 0) {
#pragma unroll
        for (int k = 0; k < NVAL; ++k) red[wave][k] = v[k];
    }
    __syncthreads();
    if (tid < NVAL) {
        float s = 0.f;
#pragma unroll
        for (int w = 0; w < NWAVES; ++w) s += red[w][tid];
        // transposed: ws[k][global_block] -> contiguous per-k rows of 256 floats
        ws[(size_t)tid * NBLOCKS + (b * BPB + blk)] = s;
    }
}

__global__ __launch_bounds__(256) void pit_finalize(const float* __restrict__ ws,
                                                    float* __restrict__ out) {
    __shared__ double stage[BATCH][NVAL];   // summed partials
    __shared__ double dists[BATCH][4][4];
    __shared__ double mins[BATCH];
    const int tid = threadIdx.x;

    // 192 active threads, (k major, b minor): the whole block reads the
    // 24 KiB ws span fully coalesced as float4.
    if (tid < BATCH * NVAL) {
        const int k = tid / BATCH, bb = tid % BATCH;
        const f4* p = (const f4*)(ws + (size_t)k * NBLOCKS + bb * BPB);
        double s0 = 0.0, s1 = 0.0, s2 = 0.0, s3 = 0.0;
#pragma unroll
        for (int q = 0; q < 8; q += 4) {         // 8 f4 = 32 partials
            f4 a = p[q + 0], c = p[q + 1], d = p[q + 2], e = p[q + 3];
            s0 += (double)a.x + (double)a.y + (double)a.z + (double)a.w;
            s1 += (double)c.x + (double)c.y + (double)c.z + (double)c.w;
            s2 += (double)d.x + (double)d.y + (double)d.z + (double)d.w;
            s3 += (double)e.x + (double)e.y + (double)e.z + (double)e.w;
        }
        stage[bb][k] = (s0 + s1) + (s2 + s3);
    }
    __syncthreads();

    if (tid < BATCH * 16) {                 // 128 threads
        const int bb = tid / 16, ij = tid % 16, i = ij / 4, j = ij % 4;
        dists[bb][i][j] = (stage[bb][4 + i] + stage[bb][j]
                           - 2.0 * stage[bb][8 + i * 4 + j]) / (double)DLEN;
    }
    __syncthreads();

    if (tid < BATCH) {
        const int bb = tid;
        double best = 1e300;
        int bestp = 0;
        for (int p = 0; p < 24; ++p) {
            double c = 0.0;
#pragma unroll
            for (int i = 0; i < 4; ++i) c += dists[bb][i][PERMS[p][i]];
            if (c < best) { best = c; bestp = p; }   // strict < => first min (jnp.argmin)
        }
        mins[bb] = best;
#pragma unroll
        for (int i = 0; i < 4; ++i)
            out[1 + bb * 4 + i] = (float)PERMS[bestp][i];
    }
    __syncthreads();

    if (tid == 0) {
        double tot = 0.0;
        for (int bb = 0; bb < BATCH; ++bb) tot += mins[bb];
        out[0] = (float)tot;
    }
}

extern "C" void kernel_launch(void* const* d_in, const int* in_sizes, int n_in,
                              void* d_out, int out_size, void* d_ws, size_t ws_size,
                              hipStream_t stream) {
    const float* x = (const float*)d_in[0];
    const float* y = (const float*)d_in[1];
    float* out = (float*)d_out;
    float* ws  = (float*)d_ws;     // needs NVAL*NBLOCKS*4 = 24576 bytes

    pit_reduce<<<NBLOCKS, TPB, 0, stream>>>(x, y, ws);
    pit_finalize<<<1, 256, 0, stream>>>(ws, out);
}